// Round 1
// baseline (256.946 us; speedup 1.0000x reference)
//
#include <hip/hip_runtime.h>
#include <stdint.h>

typedef __attribute__((ext_vector_type(4))) float f32x4;
typedef __attribute__((ext_vector_type(8))) short short8;
typedef unsigned short u16;

#define NH 16
#define HD 64
#define SEQ 4096
#define BATCH 4
#define NROWS (BATCH * SEQ)      // 16384
#define DIMC 1024
#define QKVC 3072
#define SCALE 0.125f

__device__ __forceinline__ u16 f2bf(float f) {
  union { float f; uint32_t u; } v; v.f = f;
  uint32_t u = v.u;
  uint32_t r = (u + 0x7fffu + ((u >> 16) & 1u)) >> 16;
  return (u16)r;
}
__device__ __forceinline__ float bf2f(u16 h) {
  union { uint32_t u; float f; } v; v.u = ((uint32_t)h) << 16;
  return v.f;
}

// ---------------- fp32 -> bf16 elementwise convert (vectorized) ----------------
__global__ __launch_bounds__(256) void cvt_kernel(const float* __restrict__ in,
                                                  u16* __restrict__ out, int n4) {
  int i = blockIdx.x * 256 + threadIdx.x;
  if (i >= n4) return;
  float4 v = ((const float4*)in)[i];
  ushort4 o;
  o.x = f2bf(v.x); o.y = f2bf(v.y); o.z = f2bf(v.z); o.w = f2bf(v.w);
  ((ushort4*)out)[i] = o;
}

// ---------------- fp32 [R][C] -> bf16 [C][R] transpose ----------------
__global__ __launch_bounds__(256) void transpose_cvt(const float* __restrict__ in,
                                                     u16* __restrict__ out, int R, int C) {
  __shared__ float t[32][33];
  int nbx = C >> 5;
  int bx = blockIdx.x % nbx, by = blockIdx.x / nbx;
  int r0 = by << 5, c0 = bx << 5;
  int tid = threadIdx.x;
#pragma unroll
  for (int i = 0; i < 4; i++) {
    int id = i * 256 + tid; int lr = id >> 5, lc = id & 31;
    t[lr][lc] = in[(size_t)(r0 + lr) * C + (c0 + lc)];
  }
  __syncthreads();
#pragma unroll
  for (int i = 0; i < 4; i++) {
    int id = i * 256 + tid; int lr = id >> 5, lc = id & 31;
    out[(size_t)(c0 + lr) * R + (r0 + lc)] = f2bf(t[lc][lr]);
  }
}

// ---------------- bf16 GEMM: C[M,N] = A[M,K] * Bt[N,K]^T ----------------
// 128x128 tile, BK=64, 4 waves (2x2), each wave 64x64 via 4x4 frags of 16x16x32.
// XOR-swizzled LDS (T2) + bijective XCD blockIdx swizzle (T1).
template <int OUT_BF16>
__global__ __launch_bounds__(256) void gemm_bt(const u16* __restrict__ A,
                                               const u16* __restrict__ Bt,
                                               void* __restrict__ Cv,
                                               int M, int N, int K) {
  __shared__ u16 As[128 * 64];
  __shared__ u16 Bs[128 * 64];
  int nbx = N >> 7;
  int nwg = gridDim.x;
  int bid = blockIdx.x;
  int cpx = nwg >> 3;                       // grids are multiples of 8
  int swz = (bid & 7) * cpx + (bid >> 3);
  int bx = swz % nbx, by = swz / nbx;
  int tid = threadIdx.x, lane = tid & 63, wv = tid >> 6;
  int wr = wv >> 1, wc = wv & 1;
  int lr = lane & 15, g = lane >> 4;
  f32x4 acc[4][4];
#pragma unroll
  for (int m = 0; m < 4; m++)
#pragma unroll
    for (int n = 0; n < 4; n++) acc[m][n] = (f32x4){0.f, 0.f, 0.f, 0.f};

  const u16* Ap = A + (size_t)(by * 128) * K;
  const u16* Bp = Bt + (size_t)(bx * 128) * K;

  for (int kt = 0; kt < K; kt += 64) {
#pragma unroll
    for (int p = 0; p < 4; p++) {
      int cid = p * 256 + tid;
      int row = cid >> 3, ch = cid & 7;
      int sw = (ch ^ (row & 7)) << 3;
      *(uint4*)&As[row * 64 + sw] = *(const uint4*)(Ap + (size_t)row * K + kt + ch * 8);
      *(uint4*)&Bs[row * 64 + sw] = *(const uint4*)(Bp + (size_t)row * K + kt + ch * 8);
    }
    __syncthreads();
#pragma unroll
    for (int kk = 0; kk < 64; kk += 32) {
      short8 af[4], bfr[4];
#pragma unroll
      for (int m = 0; m < 4; m++) {
        int row = wr * 64 + m * 16 + lr;
        int ci = (kk >> 3) + g;
        af[m] = *(const short8*)&As[row * 64 + ((ci ^ (row & 7)) << 3)];
      }
#pragma unroll
      for (int n = 0; n < 4; n++) {
        int row = wc * 64 + n * 16 + lr;
        int ci = (kk >> 3) + g;
        bfr[n] = *(const short8*)&Bs[row * 64 + ((ci ^ (row & 7)) << 3)];
      }
#pragma unroll
      for (int m = 0; m < 4; m++)
#pragma unroll
        for (int n = 0; n < 4; n++)
          acc[m][n] = __builtin_amdgcn_mfma_f32_16x16x32_bf16(af[m], bfr[n], acc[m][n], 0, 0, 0);
    }
    __syncthreads();
  }
  int rb = by * 128 + wr * 64, cb = bx * 128 + wc * 64;
#pragma unroll
  for (int m = 0; m < 4; m++)
#pragma unroll
    for (int n = 0; n < 4; n++)
#pragma unroll
      for (int r = 0; r < 4; r++) {
        int rg = rb + m * 16 + g * 4 + r;
        int cg = cb + n * 16 + lr;
        float v = acc[m][n][r];
        if (OUT_BF16)
          ((u16*)Cv)[(size_t)rg * N + cg] = f2bf(v);
        else
          ((float*)Cv)[(size_t)rg * N + cg] = v;
      }
}

// ---------------- chunk means of K and V ----------------
__global__ void chunk_sums(const u16* __restrict__ qkv, float* __restrict__ ck,
                           float* __restrict__ cv) {
  int blk = blockIdx.x;  // ((b*16+h)*64 + c)
  int c = blk & 63, h = (blk >> 6) & 15, b = blk >> 10;
  int d = threadIdx.x;
  const u16* base = qkv + (size_t)(b * SEQ + c * 64) * QKVC + 1024 + h * 64 + d;
  float sk = 0.f, sv = 0.f;
  for (int r = 0; r < 64; r++) {
    sk += bf2f(base[(size_t)r * QKVC]);
    sv += bf2f(base[(size_t)r * QKVC + 1024]);
  }
  ck[(size_t)blk * 64 + d] = sk * 0.015625f;
  cv[(size_t)blk * 64 + d] = sv * 0.015625f;
}

// ---------------- exclusive cumsum over chunks ----------------
__global__ void cumsum_excl(const float* __restrict__ ck, const float* __restrict__ cv,
                            float* __restrict__ cuk, float* __restrict__ cuv) {
  int bh = blockIdx.x;
  int d = threadIdx.x;
  float ak = 0.f, av = 0.f;
  for (int c = 0; c < 64; c++) {
    size_t i = ((size_t)bh * 64 + c) * 64 + d;
    cuk[i] = ak; cuv[i] = av;
    ak += ck[i]; av += cv[i];
  }
}

// ---------------- per-chunk attention + cross term ----------------
// One block per (b,h,chunk): S=QK^T (MFMA), causal softmax, O=PV (MFMA),
// cross logit via extra 1-column MFMA against cum_k.
__global__ __launch_bounds__(256) void attn_kernel(const u16* __restrict__ qkv,
                                                   const float* __restrict__ cuk,
                                                   const float* __restrict__ cuv,
                                                   u16* __restrict__ out) {
  int blk = blockIdx.x;
  int c = blk & 63, h = (blk >> 6) & 15, b = blk >> 10;
  int row0 = b * SEQ + c * 64;
  __shared__ u16 q_s[64][80];
  __shared__ u16 k_s[64][80];
  __shared__ u16 vt_s[64][80];   // V transposed: vt_s[d][krow]
  __shared__ u16 p_s[64][80];
  __shared__ u16 ck_s[64];
  __shared__ float cv_s[64];
  int tid = threadIdx.x;
  {
    int r = tid >> 2, qt = tid & 3;
    const u16* rp = qkv + (size_t)(row0 + r) * QKVC + h * 64 + qt * 16;
    uint4 q0 = *(const uint4*)rp;          uint4 q1 = *(const uint4*)(rp + 8);
    uint4 k0 = *(const uint4*)(rp + 1024); uint4 k1 = *(const uint4*)(rp + 1032);
    uint4 v0 = *(const uint4*)(rp + 2048); uint4 v1 = *(const uint4*)(rp + 2056);
    *(uint4*)&q_s[r][qt * 16] = q0;     *(uint4*)&q_s[r][qt * 16 + 8] = q1;
    *(uint4*)&k_s[r][qt * 16] = k0;     *(uint4*)&k_s[r][qt * 16 + 8] = k1;
    const u16* vv0 = (const u16*)&v0;   const u16* vv1 = (const u16*)&v1;
#pragma unroll
    for (int j = 0; j < 8; j++) vt_s[qt * 16 + j][r] = vv0[j];
#pragma unroll
    for (int j = 0; j < 8; j++) vt_s[qt * 16 + 8 + j][r] = vv1[j];
    if (tid < 64) {
      ck_s[tid] = f2bf(cuk[(size_t)blk * 64 + tid]);
      cv_s[tid] = cuv[(size_t)blk * 64 + tid];
    }
  }
  __syncthreads();

  int lane = tid & 63, w = tid >> 6;
  int lr = lane & 15, g = lane >> 4;
  f32x4 accS[4];
#pragma unroll
  for (int n = 0; n < 4; n++) accS[n] = (f32x4){0.f, 0.f, 0.f, 0.f};
  f32x4 accC = (f32x4){0.f, 0.f, 0.f, 0.f};
  short8 zf = (short8){0, 0, 0, 0, 0, 0, 0, 0};
#pragma unroll
  for (int kt = 0; kt < 2; kt++) {
    int lk = kt * 32 + g * 8;
    short8 af = *(const short8*)&q_s[w * 16 + lr][lk];
    short8 cf = (lr == 0) ? *(const short8*)&ck_s[lk] : zf;
    accC = __builtin_amdgcn_mfma_f32_16x16x32_bf16(af, cf, accC, 0, 0, 0);
#pragma unroll
    for (int n = 0; n < 4; n++) {
      short8 bf = *(const short8*)&k_s[n * 16 + lr][lk];
      accS[n] = __builtin_amdgcn_mfma_f32_16x16x32_bf16(af, bf, accS[n], 0, 0, 0);
    }
  }
  float crossv[4];
#pragma unroll
  for (int r4 = 0; r4 < 4; r4++) {
    int row = w * 16 + g * 4 + r4;
    float x[4];
    float mx = -3.4e38f;
#pragma unroll
    for (int n = 0; n < 4; n++) {
      int col = n * 16 + lr;
      x[n] = ((col & 63) > (row & 63)) ? -65000.0f : accS[n][r4] * SCALE;
      mx = fmaxf(mx, x[n]);
    }
    mx = fmaxf(mx, __shfl_xor(mx, 1));
    mx = fmaxf(mx, __shfl_xor(mx, 2));
    mx = fmaxf(mx, __shfl_xor(mx, 4));
    mx = fmaxf(mx, __shfl_xor(mx, 8));
    float p[4], sum = 0.f;
#pragma unroll
    for (int n = 0; n < 4; n++) { p[n] = __expf(x[n] - mx); sum += p[n]; }
    sum += __shfl_xor(sum, 1);
    sum += __shfl_xor(sum, 2);
    sum += __shfl_xor(sum, 4);
    sum += __shfl_xor(sum, 8);
    float inv = 1.0f / sum;
#pragma unroll
    for (int n = 0; n < 4; n++) p_s[row][n * 16 + lr] = f2bf(p[n] * inv);
    float sg = 1.0f / (1.0f + __expf(-accC[r4] * SCALE));
    crossv[r4] = __shfl(sg, (lane & 48));
  }
  __syncthreads();
  f32x4 accO[4];
#pragma unroll
  for (int n = 0; n < 4; n++) accO[n] = (f32x4){0.f, 0.f, 0.f, 0.f};
#pragma unroll
  for (int kt = 0; kt < 2; kt++) {
    int lk = kt * 32 + g * 8;
    short8 pf = *(const short8*)&p_s[w * 16 + lr][lk];
#pragma unroll
    for (int n = 0; n < 4; n++) {
      short8 vf = *(const short8*)&vt_s[n * 16 + lr][lk];
      accO[n] = __builtin_amdgcn_mfma_f32_16x16x32_bf16(pf, vf, accO[n], 0, 0, 0);
    }
  }
#pragma unroll
  for (int n = 0; n < 4; n++)
#pragma unroll
    for (int r4 = 0; r4 < 4; r4++) {
      int row = w * 16 + g * 4 + r4;
      int col = n * 16 + lr;
      float v = accO[n][r4] + crossv[r4] * cv_s[col] * 0.5f;
      out[(size_t)(row0 + row) * DIMC + h * 64 + col] = f2bf(v);
    }
}

extern "C" void kernel_launch(void* const* d_in, const int* in_sizes, int n_in,
                              void* d_out, int out_size, void* d_ws, size_t ws_size,
                              hipStream_t stream) {
  const float* x = (const float*)d_in[0];
  const float* Wqkv = (const float*)d_in[1];
  const float* Wout = (const float*)d_in[2];
  char* ws = (char*)d_ws;
  size_t off = 0;
  auto alloc = [&](size_t b) {
    void* p = ws + off;
    off += (b + 255) & ~(size_t)255;
    return p;
  };
  u16* xb = (u16*)alloc((size_t)NROWS * DIMC * 2);        // 32MB, reused as attnb
  u16* wqt = (u16*)alloc((size_t)QKVC * DIMC * 2);        // 6MB
  u16* wot = (u16*)alloc((size_t)DIMC * DIMC * 2);        // 2MB
  u16* qkvb = (u16*)alloc((size_t)NROWS * QKVC * 2);      // 96MB
  float* chk = (float*)alloc((size_t)4096 * 64 * 4);
  float* chv = (float*)alloc((size_t)4096 * 64 * 4);
  float* cuk = (float*)alloc((size_t)4096 * 64 * 4);
  float* cuv = (float*)alloc((size_t)4096 * 64 * 4);
  u16* attnb = xb;

  cvt_kernel<<<16384, 256, 0, stream>>>(x, xb, NROWS * DIMC / 4);
  transpose_cvt<<<3072, 256, 0, stream>>>(Wqkv, wqt, DIMC, QKVC);
  transpose_cvt<<<1024, 256, 0, stream>>>(Wout, wot, DIMC, DIMC);
  gemm_bt<1><<<3072, 256, 0, stream>>>(xb, wqt, qkvb, NROWS, QKVC, DIMC);
  chunk_sums<<<4096, 64, 0, stream>>>(qkvb, chk, chv);
  cumsum_excl<<<64, 64, 0, stream>>>(chk, chv, cuk, cuv);
  attn_kernel<<<4096, 256, 0, stream>>>(qkvb, cuk, cuv, attnb);
  gemm_bt<0><<<1024, 256, 0, stream>>>(attnb, wot, d_out, NROWS, DIMC, DIMC);
}

// Round 2
// 244.706 us; speedup vs baseline: 1.0500x; 1.0500x over previous
//
#include <hip/hip_runtime.h>
#include <stdint.h>

typedef __attribute__((ext_vector_type(4))) float f32x4;
typedef __attribute__((ext_vector_type(8))) short short8;
typedef unsigned short u16;

#define NH 16
#define HD 64
#define SEQ 4096
#define BATCH 4
#define NROWS (BATCH * SEQ)      // 16384
#define DIMC 1024
#define QKVC 3072
#define SCALE 0.125f

__device__ __forceinline__ u16 f2bf(float f) {
  union { float f; uint32_t u; } v; v.f = f;
  uint32_t u = v.u;
  uint32_t r = (u + 0x7fffu + ((u >> 16) & 1u)) >> 16;
  return (u16)r;
}
__device__ __forceinline__ float bf2f(u16 h) {
  union { uint32_t u; float f; } v; v.u = ((uint32_t)h) << 16;
  return v.f;
}

// ---------------- fp32 -> bf16 elementwise convert (vectorized) ----------------
__global__ __launch_bounds__(256) void cvt_kernel(const float* __restrict__ in,
                                                  u16* __restrict__ out, int n4) {
  int i = blockIdx.x * 256 + threadIdx.x;
  if (i >= n4) return;
  float4 v = ((const float4*)in)[i];
  ushort4 o;
  o.x = f2bf(v.x); o.y = f2bf(v.y); o.z = f2bf(v.z); o.w = f2bf(v.w);
  ((ushort4*)out)[i] = o;
}

// ---------------- fp32 [R][C] -> bf16 [C][R] transpose ----------------
__global__ __launch_bounds__(256) void transpose_cvt(const float* __restrict__ in,
                                                     u16* __restrict__ out, int R, int C) {
  __shared__ float t[32][33];
  int nbx = C >> 5;
  int bx = blockIdx.x % nbx, by = blockIdx.x / nbx;
  int r0 = by << 5, c0 = bx << 5;
  int tid = threadIdx.x;
#pragma unroll
  for (int i = 0; i < 4; i++) {
    int id = i * 256 + tid; int lr = id >> 5, lc = id & 31;
    t[lr][lc] = in[(size_t)(r0 + lr) * C + (c0 + lc)];
  }
  __syncthreads();
#pragma unroll
  for (int i = 0; i < 4; i++) {
    int id = i * 256 + tid; int lr = id >> 5, lc = id & 31;
    out[(size_t)(c0 + lr) * R + (r0 + lc)] = f2bf(t[lc][lr]);
  }
}

// ---------------- bf16 GEMM: C[M,N] = A[M,K] * Bt[N,K]^T ----------------
// BM=256, BN=128, BK=64. 512 threads = 8 waves (4 M x 2 N), per-wave 64x64.
// 3-buffer LDS rotation (144 KiB): tile t+2 staged via global_load_lds while
// computing tile t; counted s_waitcnt vmcnt(6) per K-tile (never 0 in loop).
// LDS swizzle: 16B chunk c stored at c ^ (row&7); global source pre-swizzled
// so global_load_lds linear dest realizes it (rule #21).
template <int OUT_BF16>
__global__ __launch_bounds__(512, 2) void gemm_bt(const u16* __restrict__ A,
                                                  const u16* __restrict__ Bt,
                                                  void* __restrict__ Cv,
                                                  int M, int N, int K) {
  // per buffer: A 256x64 (16384 u16) then B 128x64 (8192 u16)
  __shared__ __align__(16) u16 lds3[3][24576];
  int nbx = N >> 7;
  int nwg = gridDim.x;
  int bid = blockIdx.x;
  int cpx = nwg >> 3;                       // grids are multiples of 8
  int swz = (bid & 7) * cpx + (bid >> 3);
  int bx = swz % nbx, by = swz / nbx;
  int tid = threadIdx.x, lane = tid & 63, wv = tid >> 6;
  int wr = wv >> 1, wc = wv & 1;            // wave grid 4 (M) x 2 (N)
  int lr = lane & 15, g = lane >> 4;
  int rx = lr & 7;
  int rsub = lane >> 3;                     // staging: row within 8-row unit
  int clog = (lane & 7) ^ rsub;             // staging: logical (global) chunk

  const u16* Ap = A + (size_t)(by * 256) * K;
  const u16* Bp = Bt + (size_t)(bx * 128) * K;

  f32x4 acc[4][4];
#pragma unroll
  for (int m = 0; m < 4; m++)
#pragma unroll
    for (int n = 0; n < 4; n++) acc[m][n] = (f32x4){0.f, 0.f, 0.f, 0.f};

  short8 a[2][2], b0[2][2], b1[2][2];

#define ISSUE(L, SKT, SB) do {                                                  \
    int unit_ = (L) * 8 + wv;                                                   \
    const u16* g_; u16* l_;                                                     \
    if (unit_ < 32) {                                                           \
      int row_ = unit_ * 8 + rsub;                                              \
      g_ = Ap + (size_t)row_ * K + (SKT) * 64 + clog * 8;                       \
      l_ = &lds3[SB][unit_ * 512];                                              \
    } else {                                                                    \
      int row_ = (unit_ - 32) * 8 + rsub;                                       \
      g_ = Bp + (size_t)row_ * K + (SKT) * 64 + clog * 8;                       \
      l_ = &lds3[SB][16384 + (unit_ - 32) * 512];                               \
    }                                                                           \
    __builtin_amdgcn_global_load_lds(                                           \
        (const __attribute__((address_space(1))) uint32_t*)g_,                  \
        (__attribute__((address_space(3))) uint32_t*)l_, 16, 0, 0);             \
  } while (0)

#define LOADA(MH) do {                                                          \
    _Pragma("unroll")                                                           \
    for (int m2 = 0; m2 < 2; m2++) {                                            \
      int row_ = wr * 64 + ((MH) * 2 + m2) * 16 + lr;                           \
      const u16* bp_ = &lds3[cur][row_ * 64];                                   \
      _Pragma("unroll")                                                         \
      for (int s = 0; s < 2; s++)                                               \
        a[m2][s] = *(const short8*)(bp_ + (((s * 4 + g) ^ rx) << 3));           \
    }                                                                           \
  } while (0)

#define LOADB(NH, BREG) do {                                                    \
    _Pragma("unroll")                                                           \
    for (int n2 = 0; n2 < 2; n2++) {                                            \
      int row_ = wc * 64 + ((NH) * 2 + n2) * 16 + lr;                           \
      const u16* bp_ = &lds3[cur][16384 + row_ * 64];                           \
      _Pragma("unroll")                                                         \
      for (int s = 0; s < 2; s++)                                               \
        BREG[n2][s] = *(const short8*)(bp_ + (((s * 4 + g) ^ rx) << 3));        \
    }                                                                           \
  } while (0)

#define MFMA_Q(MH, NH, BREG) do {                                               \
    _Pragma("unroll")                                                           \
    for (int s = 0; s < 2; s++)                                                 \
      _Pragma("unroll")                                                         \
      for (int m2 = 0; m2 < 2; m2++)                                            \
        _Pragma("unroll")                                                       \
        for (int n2 = 0; n2 < 2; n2++)                                          \
          acc[(MH) * 2 + m2][(NH) * 2 + n2] =                                   \
              __builtin_amdgcn_mfma_f32_16x16x32_bf16(                          \
                  a[m2][s], BREG[n2][s], acc[(MH) * 2 + m2][(NH) * 2 + n2],     \
                  0, 0, 0);                                                     \
  } while (0)

  int NT = K >> 6;
  // prologue: stage tiles 0 and 1, counted wait leaves tile1 in flight
#pragma unroll
  for (int l = 0; l < 6; l++) ISSUE(l, 0, 0);
#pragma unroll
  for (int l = 0; l < 6; l++) ISSUE(l, 1, 1);
  asm volatile("s_waitcnt vmcnt(6)" ::: "memory");
  __builtin_amdgcn_s_barrier();

  int cur = 0;
  for (int kt = 0; kt < NT; kt++) {
    int st = (kt + 2 < NT);
    int sb = cur + 2; if (sb >= 3) sb -= 3;
    int skt = kt + 2;
    // ---- P0: A(mh0) + B(nh0) frags; issue 2 loads; MFMA quadrant (0,0)
    LOADA(0);
    LOADB(0, b0);
    if (st) { ISSUE(0, skt, sb); ISSUE(1, skt, sb); }
    __builtin_amdgcn_s_barrier();
    asm volatile("s_waitcnt lgkmcnt(0)" ::: "memory");
    __builtin_amdgcn_s_setprio(1);
    MFMA_Q(0, 0, b0);
    __builtin_amdgcn_s_setprio(0);
    __builtin_amdgcn_s_barrier();
    // ---- P1: B(nh1) frags; issue 2; MFMA (0,1)
    LOADB(1, b1);
    if (st) { ISSUE(2, skt, sb); ISSUE(3, skt, sb); }
    __builtin_amdgcn_s_barrier();
    asm volatile("s_waitcnt lgkmcnt(0)" ::: "memory");
    __builtin_amdgcn_s_setprio(1);
    MFMA_Q(0, 1, b1);
    __builtin_amdgcn_s_setprio(0);
    __builtin_amdgcn_s_barrier();
    // ---- P2: A(mh1) frags; issue 2; MFMA (1,1)
    LOADA(1);
    if (st) { ISSUE(4, skt, sb); ISSUE(5, skt, sb); }
    __builtin_amdgcn_s_barrier();
    asm volatile("s_waitcnt lgkmcnt(0)" ::: "memory");
    __builtin_amdgcn_s_setprio(1);
    MFMA_Q(1, 1, b1);
    __builtin_amdgcn_s_setprio(0);
    __builtin_amdgcn_s_barrier();
    // ---- P3: MFMA (1,0) reusing a(mh1), b0; counted vmcnt; barrier
    __builtin_amdgcn_s_setprio(1);
    MFMA_Q(1, 0, b0);
    __builtin_amdgcn_s_setprio(0);
    __builtin_amdgcn_sched_barrier(0);
    if (kt < NT - 2)
      asm volatile("s_waitcnt vmcnt(6)" ::: "memory");
    else
      asm volatile("s_waitcnt vmcnt(0)" ::: "memory");
    __builtin_amdgcn_sched_barrier(0);
    __builtin_amdgcn_s_barrier();
    cur = cur + 1; if (cur >= 3) cur -= 3;
  }

#undef ISSUE
#undef LOADA
#undef LOADB
#undef MFMA_Q

  int rb = by * 256 + wr * 64, cb = bx * 128 + wc * 64;
#pragma unroll
  for (int m = 0; m < 4; m++)
#pragma unroll
    for (int n = 0; n < 4; n++)
#pragma unroll
      for (int r = 0; r < 4; r++) {
        int rg = rb + m * 16 + g * 4 + r;
        int cg = cb + n * 16 + lr;
        float v = acc[m][n][r];
        if (OUT_BF16)
          ((u16*)Cv)[(size_t)rg * N + cg] = f2bf(v);
        else
          ((float*)Cv)[(size_t)rg * N + cg] = v;
      }
}

// ---------------- chunk means of K and V ----------------
__global__ void chunk_sums(const u16* __restrict__ qkv, float* __restrict__ ck,
                           float* __restrict__ cv) {
  int blk = blockIdx.x;  // ((b*16+h)*64 + c)
  int c = blk & 63, h = (blk >> 6) & 15, b = blk >> 10;
  int d = threadIdx.x;
  const u16* base = qkv + (size_t)(b * SEQ + c * 64) * QKVC + 1024 + h * 64 + d;
  float sk = 0.f, sv = 0.f;
  for (int r = 0; r < 64; r++) {
    sk += bf2f(base[(size_t)r * QKVC]);
    sv += bf2f(base[(size_t)r * QKVC + 1024]);
  }
  ck[(size_t)blk * 64 + d] = sk * 0.015625f;
  cv[(size_t)blk * 64 + d] = sv * 0.015625f;
}

// ---------------- exclusive cumsum over chunks ----------------
__global__ void cumsum_excl(const float* __restrict__ ck, const float* __restrict__ cv,
                            float* __restrict__ cuk, float* __restrict__ cuv) {
  int bh = blockIdx.x;
  int d = threadIdx.x;
  float ak = 0.f, av = 0.f;
  for (int c = 0; c < 64; c++) {
    size_t i = ((size_t)bh * 64 + c) * 64 + d;
    cuk[i] = ak; cuv[i] = av;
    ak += ck[i]; av += cv[i];
  }
}

// ---------------- per-chunk attention + cross term ----------------
__global__ __launch_bounds__(256) void attn_kernel(const u16* __restrict__ qkv,
                                                   const float* __restrict__ cuk,
                                                   const float* __restrict__ cuv,
                                                   u16* __restrict__ out) {
  int blk = blockIdx.x;
  int c = blk & 63, h = (blk >> 6) & 15, b = blk >> 10;
  int row0 = b * SEQ + c * 64;
  __shared__ u16 q_s[64][80];
  __shared__ u16 k_s[64][80];
  __shared__ u16 vt_s[64][80];   // V transposed: vt_s[d][krow]
  __shared__ u16 p_s[64][80];
  __shared__ u16 ck_s[64];
  __shared__ float cv_s[64];
  int tid = threadIdx.x;
  {
    int r = tid >> 2, qt = tid & 3;
    const u16* rp = qkv + (size_t)(row0 + r) * QKVC + h * 64 + qt * 16;
    uint4 q0 = *(const uint4*)rp;          uint4 q1 = *(const uint4*)(rp + 8);
    uint4 k0 = *(const uint4*)(rp + 1024); uint4 k1 = *(const uint4*)(rp + 1032);
    uint4 v0 = *(const uint4*)(rp + 2048); uint4 v1 = *(const uint4*)(rp + 2056);
    *(uint4*)&q_s[r][qt * 16] = q0;     *(uint4*)&q_s[r][qt * 16 + 8] = q1;
    *(uint4*)&k_s[r][qt * 16] = k0;     *(uint4*)&k_s[r][qt * 16 + 8] = k1;
    const u16* vv0 = (const u16*)&v0;   const u16* vv1 = (const u16*)&v1;
#pragma unroll
    for (int j = 0; j < 8; j++) vt_s[qt * 16 + j][r] = vv0[j];
#pragma unroll
    for (int j = 0; j < 8; j++) vt_s[qt * 16 + 8 + j][r] = vv1[j];
    if (tid < 64) {
      ck_s[tid] = f2bf(cuk[(size_t)blk * 64 + tid]);
      cv_s[tid] = cuv[(size_t)blk * 64 + tid];
    }
  }
  __syncthreads();

  int lane = tid & 63, w = tid >> 6;
  int lr = lane & 15, g = lane >> 4;
  f32x4 accS[4];
#pragma unroll
  for (int n = 0; n < 4; n++) accS[n] = (f32x4){0.f, 0.f, 0.f, 0.f};
  f32x4 accC = (f32x4){0.f, 0.f, 0.f, 0.f};
  short8 zf = (short8){0, 0, 0, 0, 0, 0, 0, 0};
#pragma unroll
  for (int kt = 0; kt < 2; kt++) {
    int lk = kt * 32 + g * 8;
    short8 af = *(const short8*)&q_s[w * 16 + lr][lk];
    short8 cf = (lr == 0) ? *(const short8*)&ck_s[lk] : zf;
    accC = __builtin_amdgcn_mfma_f32_16x16x32_bf16(af, cf, accC, 0, 0, 0);
#pragma unroll
    for (int n = 0; n < 4; n++) {
      short8 bf = *(const short8*)&k_s[n * 16 + lr][lk];
      accS[n] = __builtin_amdgcn_mfma_f32_16x16x32_bf16(af, bf, accS[n], 0, 0, 0);
    }
  }
  float crossv[4];
#pragma unroll
  for (int r4 = 0; r4 < 4; r4++) {
    int row = w * 16 + g * 4 + r4;
    float x[4];
    float mx = -3.4e38f;
#pragma unroll
    for (int n = 0; n < 4; n++) {
      int col = n * 16 + lr;
      x[n] = ((col & 63) > (row & 63)) ? -65000.0f : accS[n][r4] * SCALE;
      mx = fmaxf(mx, x[n]);
    }
    mx = fmaxf(mx, __shfl_xor(mx, 1));
    mx = fmaxf(mx, __shfl_xor(mx, 2));
    mx = fmaxf(mx, __shfl_xor(mx, 4));
    mx = fmaxf(mx, __shfl_xor(mx, 8));
    float p[4], sum = 0.f;
#pragma unroll
    for (int n = 0; n < 4; n++) { p[n] = __expf(x[n] - mx); sum += p[n]; }
    sum += __shfl_xor(sum, 1);
    sum += __shfl_xor(sum, 2);
    sum += __shfl_xor(sum, 4);
    sum += __shfl_xor(sum, 8);
    float inv = 1.0f / sum;
#pragma unroll
    for (int n = 0; n < 4; n++) p_s[row][n * 16 + lr] = f2bf(p[n] * inv);
    float sg = 1.0f / (1.0f + __expf(-accC[r4] * SCALE));
    crossv[r4] = __shfl(sg, (lane & 48));
  }
  __syncthreads();
  f32x4 accO[4];
#pragma unroll
  for (int n = 0; n < 4; n++) accO[n] = (f32x4){0.f, 0.f, 0.f, 0.f};
#pragma unroll
  for (int kt = 0; kt < 2; kt++) {
    int lk = kt * 32 + g * 8;
    short8 pf = *(const short8*)&p_s[w * 16 + lr][lk];
#pragma unroll
    for (int n = 0; n < 4; n++) {
      short8 vf = *(const short8*)&vt_s[n * 16 + lr][lk];
      accO[n] = __builtin_amdgcn_mfma_f32_16x16x32_bf16(pf, vf, accO[n], 0, 0, 0);
    }
  }
#pragma unroll
  for (int n = 0; n < 4; n++)
#pragma unroll
    for (int r4 = 0; r4 < 4; r4++) {
      int row = w * 16 + g * 4 + r4;
      int col = n * 16 + lr;
      float v = accO[n][r4] + crossv[r4] * cv_s[col] * 0.5f;
      out[(size_t)(row0 + row) * DIMC + h * 64 + col] = f2bf(v);
    }
}

extern "C" void kernel_launch(void* const* d_in, const int* in_sizes, int n_in,
                              void* d_out, int out_size, void* d_ws, size_t ws_size,
                              hipStream_t stream) {
  const float* x = (const float*)d_in[0];
  const float* Wqkv = (const float*)d_in[1];
  const float* Wout = (const float*)d_in[2];
  char* ws = (char*)d_ws;
  size_t off = 0;
  auto alloc = [&](size_t b) {
    void* p = ws + off;
    off += (b + 255) & ~(size_t)255;
    return p;
  };
  u16* xb = (u16*)alloc((size_t)NROWS * DIMC * 2);        // 32MB, reused as attnb
  u16* wqt = (u16*)alloc((size_t)QKVC * DIMC * 2);        // 6MB
  u16* wot = (u16*)alloc((size_t)DIMC * DIMC * 2);        // 2MB
  u16* qkvb = (u16*)alloc((size_t)NROWS * QKVC * 2);      // 96MB
  float* chk = (float*)alloc((size_t)4096 * 64 * 4);
  float* chv = (float*)alloc((size_t)4096 * 64 * 4);
  float* cuk = (float*)alloc((size_t)4096 * 64 * 4);
  float* cuv = (float*)alloc((size_t)4096 * 64 * 4);
  u16* attnb = xb;

  cvt_kernel<<<16384, 256, 0, stream>>>(x, xb, NROWS * DIMC / 4);
  transpose_cvt<<<3072, 256, 0, stream>>>(Wqkv, wqt, DIMC, QKVC);
  transpose_cvt<<<1024, 256, 0, stream>>>(Wout, wot, DIMC, DIMC);
  gemm_bt<1><<<1536, 512, 0, stream>>>(xb, wqt, qkvb, NROWS, QKVC, DIMC);
  chunk_sums<<<4096, 64, 0, stream>>>(qkvb, chk, chv);
  cumsum_excl<<<64, 64, 0, stream>>>(chk, chv, cuk, cuv);
  attn_kernel<<<4096, 256, 0, stream>>>(qkvb, cuk, cuv, attnb);
  gemm_bt<0><<<512, 512, 0, stream>>>(attnb, wot, d_out, NROWS, DIMC, DIMC);
}

// Round 4
// 215.373 us; speedup vs baseline: 1.1930x; 1.1362x over previous
//
#include <hip/hip_runtime.h>
#include <stdint.h>

typedef __attribute__((ext_vector_type(4))) float f32x4;
typedef __attribute__((ext_vector_type(8))) short short8;
typedef unsigned short u16;

#define NH 16
#define HD 64
#define SEQ 4096
#define BATCH 4
#define NROWS (BATCH * SEQ)      // 16384
#define DIMC 1024
#define QKVC 3072
#define SCALE 0.125f

__device__ __forceinline__ u16 f2bf(float f) {
  union { float f; uint32_t u; } v; v.f = f;
  uint32_t u = v.u;
  uint32_t r = (u + 0x7fffu + ((u >> 16) & 1u)) >> 16;
  return (u16)r;
}
__device__ __forceinline__ float bf2f(u16 h) {
  union { uint32_t u; float f; } v; v.u = ((uint32_t)h) << 16;
  return v.f;
}

// ---------------- fp32 -> bf16 elementwise convert (vectorized) ----------------
__global__ __launch_bounds__(256) void cvt_kernel(const float* __restrict__ in,
                                                  u16* __restrict__ out, int n4) {
  int i = blockIdx.x * 256 + threadIdx.x;
  if (i >= n4) return;
  float4 v = ((const float4*)in)[i];
  ushort4 o;
  o.x = f2bf(v.x); o.y = f2bf(v.y); o.z = f2bf(v.z); o.w = f2bf(v.w);
  ((ushort4*)out)[i] = o;
}

// ---------------- fp32 [R][C] -> bf16 [C][R] transpose ----------------
__global__ __launch_bounds__(256) void transpose_cvt(const float* __restrict__ in,
                                                     u16* __restrict__ out, int R, int C) {
  __shared__ float t[32][33];
  int nbx = C >> 5;
  int bx = blockIdx.x % nbx, by = blockIdx.x / nbx;
  int r0 = by << 5, c0 = bx << 5;
  int tid = threadIdx.x;
#pragma unroll
  for (int i = 0; i < 4; i++) {
    int id = i * 256 + tid; int lr = id >> 5, lc = id & 31;
    t[lr][lc] = in[(size_t)(r0 + lr) * C + (c0 + lc)];
  }
  __syncthreads();
#pragma unroll
  for (int i = 0; i < 4; i++) {
    int id = i * 256 + tid; int lr = id >> 5, lc = id & 31;
    out[(size_t)(c0 + lr) * R + (r0 + lc)] = f2bf(t[lc][lr]);
  }
}

// ---------------- bf16 GEMM: C[M,N] = A[M,K] * Bt[N,K]^T ----------------
// m201 template port: BM=BN=256, BK=64, 512 thr = 8 waves (2M x 4N),
// per-wave 128x64 (acc[8][4]). LDS 128 KiB = 2 dbuf x (A 256x64 + B 256x64).
// 4 phases/K-tile, 16 MFMA/phase, quadrants (0,0)(0,1)(1,1)(1,0).
// Staging (region-liveness verified):
//   P1 -> A1(t+1)  [other buffer; t-1 readers done]
//   P3 -> B0(t+2)  [B last read at P2]
//   P4 -> B1(t+2) + A0(t+2)  [A last read at P3 (a1 straddles halves)]
//   vmcnt(6) at P4 retires exactly tile t+1 (8 oldest of 14).
template <int OUT_BF16>
__global__ __launch_bounds__(512, 2) void gemm_bt(const u16* __restrict__ A,
                                                  const u16* __restrict__ Bt,
                                                  void* __restrict__ Cv,
                                                  int M, int N, int K) {
  __shared__ __align__(16) u16 lds2[2][32768];   // per dbuf: A[0..16383], B[16384..32767]
  int nbx = N >> 8;
  int nwg = gridDim.x;
  int bid = blockIdx.x;
  int cpx = nwg >> 3;                       // grids are multiples of 8
  int swz = (bid & 7) * cpx + (bid >> 3);
  int bx = swz % nbx, by = swz / nbx;
  int tid = threadIdx.x, lane = tid & 63, wv = tid >> 6;
  int wr = wv >> 2, wc = wv & 3;            // wave grid 2 (M) x 4 (N)
  int lr = lane & 15, g = lane >> 4;
  int rx = lr & 7;
  int rsub = lane >> 3;                     // staging: row within 8-row unit
  int clog = (lane & 7) ^ rsub;             // staging: logical (global) chunk

  const u16* Ap = A + (size_t)(by * 256) * K;
  const u16* Bp = Bt + (size_t)(bx * 256) * K;

  f32x4 acc[8][4];
#pragma unroll
  for (int m = 0; m < 8; m++)
#pragma unroll
    for (int n = 0; n < 4; n++) acc[m][n] = (f32x4){0.f, 0.f, 0.f, 0.f};

  short8 a0[4][2], a1[4][2], b0[2][2], b1[2][2];

#define ISSUE_A(HALF, L, T) do {                                                \
    int ru_ = (HALF) * 128 + (L) * 64 + wv * 8;                                 \
    const u16* g_ = Ap + (size_t)(ru_ + rsub) * K + (T) * 64 + clog * 8;        \
    __builtin_amdgcn_global_load_lds(                                           \
        (const __attribute__((address_space(1))) uint32_t*)g_,                  \
        (__attribute__((address_space(3))) uint32_t*)&lds2[(T) & 1][ru_ * 64],  \
        16, 0, 0);                                                              \
  } while (0)

#define ISSUE_B(HALF, L, T) do {                                                \
    int ru_ = (HALF) * 128 + (L) * 64 + wv * 8;                                 \
    const u16* g_ = Bp + (size_t)(ru_ + rsub) * K + (T) * 64 + clog * 8;        \
    __builtin_amdgcn_global_load_lds(                                           \
        (const __attribute__((address_space(1))) uint32_t*)g_,                  \
        (__attribute__((address_space(3)))                                      \
             uint32_t*)&lds2[(T) & 1][16384 + ru_ * 64],                        \
        16, 0, 0);                                                              \
  } while (0)

#define LDA(DST, MH, T) do {                                                    \
    _Pragma("unroll")                                                           \
    for (int m2 = 0; m2 < 4; m2++) {                                            \
      int row_ = wr * 128 + ((MH) * 4 + m2) * 16 + lr;                          \
      const u16* bp_ = &lds2[(T) & 1][row_ * 64];                               \
      _Pragma("unroll")                                                         \
      for (int s = 0; s < 2; s++)                                               \
        DST[m2][s] = *(const short8*)(bp_ + (((s * 4 + g) ^ rx) << 3));         \
    }                                                                           \
  } while (0)

#define LDB(DST, NHh, T) do {                                                   \
    _Pragma("unroll")                                                           \
    for (int n2 = 0; n2 < 2; n2++) {                                            \
      int row_ = wc * 64 + ((NHh) * 2 + n2) * 16 + lr;                          \
      const u16* bp_ = &lds2[(T) & 1][16384 + row_ * 64];                       \
      _Pragma("unroll")                                                         \
      for (int s = 0; s < 2; s++)                                               \
        DST[n2][s] = *(const short8*)(bp_ + (((s * 4 + g) ^ rx) << 3));         \
    }                                                                           \
  } while (0)

#define MFMA_Q(MH, NHh, AA, BB) do {                                            \
    _Pragma("unroll")                                                           \
    for (int s = 0; s < 2; s++)                                                 \
      _Pragma("unroll")                                                         \
      for (int m2 = 0; m2 < 4; m2++)                                            \
        _Pragma("unroll")                                                       \
        for (int n2 = 0; n2 < 2; n2++)                                          \
          acc[(MH) * 4 + m2][(NHh) * 2 + n2] =                                  \
              __builtin_amdgcn_mfma_f32_16x16x32_bf16(                          \
                  AA[m2][s], BB[n2][s], acc[(MH) * 4 + m2][(NHh) * 2 + n2],     \
                  0, 0, 0);                                                     \
  } while (0)

  int NT = K >> 6;
  // prologue: tile 0 fully + A0,B0,B1 of tile 1; retire tile 0 (vmcnt 6)
  ISSUE_A(0, 0, 0); ISSUE_A(0, 1, 0);
  ISSUE_B(0, 0, 0); ISSUE_B(0, 1, 0);
  ISSUE_B(1, 0, 0); ISSUE_B(1, 1, 0);
  ISSUE_A(1, 0, 0); ISSUE_A(1, 1, 0);
  ISSUE_A(0, 0, 1); ISSUE_A(0, 1, 1);
  ISSUE_B(0, 0, 1); ISSUE_B(0, 1, 1);
  ISSUE_B(1, 0, 1); ISSUE_B(1, 1, 1);
  __builtin_amdgcn_sched_barrier(0);
  asm volatile("s_waitcnt vmcnt(6)" ::: "memory");
  __builtin_amdgcn_sched_barrier(0);
  __builtin_amdgcn_s_barrier();

  for (int t = 0; t < NT; t++) {
    // ---- P1: read aH0 + bH0; issue A1(t+1); MFMA Q(0,0)
    LDA(a0, 0, t);
    LDB(b0, 0, t);
    if (t + 1 < NT) { ISSUE_A(1, 0, t + 1); ISSUE_A(1, 1, t + 1); }
    __builtin_amdgcn_s_barrier();
    asm volatile("s_waitcnt lgkmcnt(0)" ::: "memory");
    __builtin_amdgcn_sched_barrier(0);
    __builtin_amdgcn_s_setprio(1);
    MFMA_Q(0, 0, a0, b0);
    __builtin_amdgcn_s_setprio(0);
    __builtin_amdgcn_s_barrier();
    // ---- P2: read bH1; MFMA Q(0,1)   (no staging: A regions still live)
    LDB(b1, 1, t);
    __builtin_amdgcn_s_barrier();
    asm volatile("s_waitcnt lgkmcnt(0)" ::: "memory");
    __builtin_amdgcn_sched_barrier(0);
    __builtin_amdgcn_s_setprio(1);
    MFMA_Q(0, 1, a0, b1);
    __builtin_amdgcn_s_setprio(0);
    __builtin_amdgcn_s_barrier();
    // ---- P3: read aH1; issue B0(t+2); MFMA Q(1,1)
    LDA(a1, 1, t);
    if (t + 2 < NT) { ISSUE_B(0, 0, t + 2); ISSUE_B(0, 1, t + 2); }
    __builtin_amdgcn_s_barrier();
    asm volatile("s_waitcnt lgkmcnt(0)" ::: "memory");
    __builtin_amdgcn_sched_barrier(0);
    __builtin_amdgcn_s_setprio(1);
    MFMA_Q(1, 1, a1, b1);
    __builtin_amdgcn_s_setprio(0);
    __builtin_amdgcn_s_barrier();
    // ---- P4: issue B1(t+2) + A0(t+2) (A safe: last A-read was P3);
    //          counted vmcnt; barrier; MFMA Q(1,0)
    if (t + 2 < NT) {
      ISSUE_B(1, 0, t + 2); ISSUE_B(1, 1, t + 2);
      ISSUE_A(0, 0, t + 2); ISSUE_A(0, 1, t + 2);
    }
    __builtin_amdgcn_sched_barrier(0);
    if (t < NT - 2)
      asm volatile("s_waitcnt vmcnt(6)" ::: "memory");
    else
      asm volatile("s_waitcnt vmcnt(0)" ::: "memory");
    __builtin_amdgcn_sched_barrier(0);
    __builtin_amdgcn_s_barrier();
    __builtin_amdgcn_s_setprio(1);
    MFMA_Q(1, 0, a1, b0);
    __builtin_amdgcn_s_setprio(0);
  }

#undef ISSUE_A
#undef ISSUE_B
#undef LDA
#undef LDB
#undef MFMA_Q

  int rb = by * 256 + wr * 128, cb = bx * 256 + wc * 64;
#pragma unroll
  for (int m = 0; m < 8; m++)
#pragma unroll
    for (int n = 0; n < 4; n++)
#pragma unroll
      for (int r = 0; r < 4; r++) {
        int rg = rb + m * 16 + g * 4 + r;
        int cg = cb + n * 16 + lr;
        float v = acc[m][n][r];
        if (OUT_BF16)
          ((u16*)Cv)[(size_t)rg * N + cg] = f2bf(v);
        else
          ((float*)Cv)[(size_t)rg * N + cg] = v;
      }
}

// ---------------- chunk means of K and V ----------------
__global__ void chunk_sums(const u16* __restrict__ qkv, float* __restrict__ ck,
                           float* __restrict__ cv) {
  int blk = blockIdx.x;  // ((b*16+h)*64 + c)
  int c = blk & 63, h = (blk >> 6) & 15, b = blk >> 10;
  int d = threadIdx.x;
  const u16* base = qkv + (size_t)(b * SEQ + c * 64) * QKVC + 1024 + h * 64 + d;
  float sk = 0.f, sv = 0.f;
  for (int r = 0; r < 64; r++) {
    sk += bf2f(base[(size_t)r * QKVC]);
    sv += bf2f(base[(size_t)r * QKVC + 1024]);
  }
  ck[(size_t)blk * 64 + d] = sk * 0.015625f;
  cv[(size_t)blk * 64 + d] = sv * 0.015625f;
}

// ---------------- exclusive cumsum over chunks ----------------
__global__ void cumsum_excl(const float* __restrict__ ck, const float* __restrict__ cv,
                            float* __restrict__ cuk, float* __restrict__ cuv) {
  int bh = blockIdx.x;
  int d = threadIdx.x;
  float ak = 0.f, av = 0.f;
  for (int c = 0; c < 64; c++) {
    size_t i = ((size_t)bh * 64 + c) * 64 + d;
    cuk[i] = ak; cuv[i] = av;
    ak += ck[i]; av += cv[i];
  }
}

// ---------------- per-chunk attention + cross term ----------------
__global__ __launch_bounds__(256) void attn_kernel(const u16* __restrict__ qkv,
                                                   const float* __restrict__ cuk,
                                                   const float* __restrict__ cuv,
                                                   u16* __restrict__ out) {
  int blk = blockIdx.x;
  int c = blk & 63, h = (blk >> 6) & 15, b = blk >> 10;
  int row0 = b * SEQ + c * 64;
  __shared__ u16 q_s[64][80];
  __shared__ u16 k_s[64][80];
  __shared__ u16 vt_s[64][80];   // V transposed: vt_s[d][krow]
  __shared__ u16 p_s[64][80];
  __shared__ u16 ck_s[64];
  __shared__ float cv_s[64];
  int tid = threadIdx.x;
  {
    int r = tid >> 2, qt = tid & 3;
    const u16* rp = qkv + (size_t)(row0 + r) * QKVC + h * 64 + qt * 16;
    uint4 q0 = *(const uint4*)rp;          uint4 q1 = *(const uint4*)(rp + 8);
    uint4 k0 = *(const uint4*)(rp + 1024); uint4 k1 = *(const uint4*)(rp + 1032);
    uint4 v0 = *(const uint4*)(rp + 2048); uint4 v1 = *(const uint4*)(rp + 2056);
    *(uint4*)&q_s[r][qt * 16] = q0;     *(uint4*)&q_s[r][qt * 16 + 8] = q1;
    *(uint4*)&k_s[r][qt * 16] = k0;     *(uint4*)&k_s[r][qt * 16 + 8] = k1;
    const u16* vv0 = (const u16*)&v0;   const u16* vv1 = (const u16*)&v1;
#pragma unroll
    for (int j = 0; j < 8; j++) vt_s[qt * 16 + j][r] = vv0[j];
#pragma unroll
    for (int j = 0; j < 8; j++) vt_s[qt * 16 + 8 + j][r] = vv1[j];
    if (tid < 64) {
      ck_s[tid] = f2bf(cuk[(size_t)blk * 64 + tid]);
      cv_s[tid] = cuv[(size_t)blk * 64 + tid];
    }
  }
  __syncthreads();

  int lane = tid & 63, w = tid >> 6;
  int lr = lane & 15, g = lane >> 4;
  f32x4 accS[4];
#pragma unroll
  for (int n = 0; n < 4; n++) accS[n] = (f32x4){0.f, 0.f, 0.f, 0.f};
  f32x4 accC = (f32x4){0.f, 0.f, 0.f, 0.f};
  short8 zf = (short8){0, 0, 0, 0, 0, 0, 0, 0};
#pragma unroll
  for (int kt = 0; kt < 2; kt++) {
    int lk = kt * 32 + g * 8;
    short8 af = *(const short8*)&q_s[w * 16 + lr][lk];
    short8 cf = (lr == 0) ? *(const short8*)&ck_s[lk] : zf;
    accC = __builtin_amdgcn_mfma_f32_16x16x32_bf16(af, cf, accC, 0, 0, 0);
#pragma unroll
    for (int n = 0; n < 4; n++) {
      short8 bf = *(const short8*)&k_s[n * 16 + lr][lk];
      accS[n] = __builtin_amdgcn_mfma_f32_16x16x32_bf16(af, bf, accS[n], 0, 0, 0);
    }
  }
  float crossv[4];
#pragma unroll
  for (int r4 = 0; r4 < 4; r4++) {
    int row = w * 16 + g * 4 + r4;
    float x[4];
    float mx = -3.4e38f;
#pragma unroll
    for (int n = 0; n < 4; n++) {
      int col = n * 16 + lr;
      x[n] = ((col & 63) > (row & 63)) ? -65000.0f : accS[n][r4] * SCALE;
      mx = fmaxf(mx, x[n]);
    }
    mx = fmaxf(mx, __shfl_xor(mx, 1));
    mx = fmaxf(mx, __shfl_xor(mx, 2));
    mx = fmaxf(mx, __shfl_xor(mx, 4));
    mx = fmaxf(mx, __shfl_xor(mx, 8));
    float p[4], sum = 0.f;
#pragma unroll
    for (int n = 0; n < 4; n++) { p[n] = __expf(x[n] - mx); sum += p[n]; }
    sum += __shfl_xor(sum, 1);
    sum += __shfl_xor(sum, 2);
    sum += __shfl_xor(sum, 4);
    sum += __shfl_xor(sum, 8);
    float inv = 1.0f / sum;
#pragma unroll
    for (int n = 0; n < 4; n++) p_s[row][n * 16 + lr] = f2bf(p[n] * inv);
    float sg = 1.0f / (1.0f + __expf(-accC[r4] * SCALE));
    crossv[r4] = __shfl(sg, (lane & 48));
  }
  __syncthreads();
  f32x4 accO[4];
#pragma unroll
  for (int n = 0; n < 4; n++) accO[n] = (f32x4){0.f, 0.f, 0.f, 0.f};
#pragma unroll
  for (int kt = 0; kt < 2; kt++) {
    int lk = kt * 32 + g * 8;
    short8 pf = *(const short8*)&p_s[w * 16 + lr][lk];
#pragma unroll
    for (int n = 0; n < 4; n++) {
      short8 vf = *(const short8*)&vt_s[n * 16 + lr][lk];
      accO[n] = __builtin_amdgcn_mfma_f32_16x16x32_bf16(pf, vf, accO[n], 0, 0, 0);
    }
  }
#pragma unroll
  for (int n = 0; n < 4; n++)
#pragma unroll
    for (int r4 = 0; r4 < 4; r4++) {
      int row = w * 16 + g * 4 + r4;
      int col = n * 16 + lr;
      float v = accO[n][r4] + crossv[r4] * cv_s[col] * 0.5f;
      out[(size_t)(row0 + row) * DIMC + h * 64 + col] = f2bf(v);
    }
}

extern "C" void kernel_launch(void* const* d_in, const int* in_sizes, int n_in,
                              void* d_out, int out_size, void* d_ws, size_t ws_size,
                              hipStream_t stream) {
  const float* x = (const float*)d_in[0];
  const float* Wqkv = (const float*)d_in[1];
  const float* Wout = (const float*)d_in[2];
  char* ws = (char*)d_ws;
  size_t off = 0;
  auto alloc = [&](size_t b) {
    void* p = ws + off;
    off += (b + 255) & ~(size_t)255;
    return p;
  };
  u16* xb = (u16*)alloc((size_t)NROWS * DIMC * 2);        // 32MB, reused as attnb
  u16* wqt = (u16*)alloc((size_t)QKVC * DIMC * 2);        // 6MB
  u16* wot = (u16*)alloc((size_t)DIMC * DIMC * 2);        // 2MB
  u16* qkvb = (u16*)alloc((size_t)NROWS * QKVC * 2);      // 96MB
  float* chk = (float*)alloc((size_t)4096 * 64 * 4);
  float* chv = (float*)alloc((size_t)4096 * 64 * 4);
  float* cuk = (float*)alloc((size_t)4096 * 64 * 4);
  float* cuv = (float*)alloc((size_t)4096 * 64 * 4);
  u16* attnb = xb;

  cvt_kernel<<<16384, 256, 0, stream>>>(x, xb, NROWS * DIMC / 4);
  transpose_cvt<<<3072, 256, 0, stream>>>(Wqkv, wqt, DIMC, QKVC);
  transpose_cvt<<<1024, 256, 0, stream>>>(Wout, wot, DIMC, DIMC);
  gemm_bt<1><<<768, 512, 0, stream>>>(xb, wqt, qkvb, NROWS, QKVC, DIMC);
  chunk_sums<<<4096, 64, 0, stream>>>(qkvb, chk, chv);
  cumsum_excl<<<64, 64, 0, stream>>>(chk, chv, cuk, cuv);
  attn_kernel<<<4096, 256, 0, stream>>>(qkvb, cuk, cuv, attnb);
  gemm_bt<0><<<256, 512, 0, stream>>>(attnb, wot, d_out, NROWS, DIMC, DIMC);
}

// Round 5
// 214.145 us; speedup vs baseline: 1.1999x; 1.0057x over previous
//
#include <hip/hip_runtime.h>
#include <stdint.h>

typedef __attribute__((ext_vector_type(4))) float f32x4;
typedef __attribute__((ext_vector_type(8))) short short8;
typedef unsigned short u16;

#define NH 16
#define HD 64
#define SEQ 4096
#define BATCH 4
#define NROWS (BATCH * SEQ)      // 16384
#define DIMC 1024
#define QKVC 3072
#define SCALE 0.125f

__device__ __forceinline__ u16 f2bf(float f) {
  union { float f; uint32_t u; } v; v.f = f;
  uint32_t u = v.u;
  uint32_t r = (u + 0x7fffu + ((u >> 16) & 1u)) >> 16;
  return (u16)r;
}
__device__ __forceinline__ float bf2f(u16 h) {
  union { uint32_t u; float f; } v; v.u = ((uint32_t)h) << 16;
  return v.f;
}

// ---------------- fp32 -> bf16 elementwise convert (vectorized) ----------------
__global__ __launch_bounds__(256) void cvt_kernel(const float* __restrict__ in,
                                                  u16* __restrict__ out, int n4) {
  int i = blockIdx.x * 256 + threadIdx.x;
  if (i >= n4) return;
  float4 v = ((const float4*)in)[i];
  ushort4 o;
  o.x = f2bf(v.x); o.y = f2bf(v.y); o.z = f2bf(v.z); o.w = f2bf(v.w);
  ((ushort4*)out)[i] = o;
}

// ---------------- fp32 [R][C] -> bf16 [C][R] transpose ----------------
__global__ __launch_bounds__(256) void transpose_cvt(const float* __restrict__ in,
                                                     u16* __restrict__ out, int R, int C) {
  __shared__ float t[32][33];
  int nbx = C >> 5;
  int bx = blockIdx.x % nbx, by = blockIdx.x / nbx;
  int r0 = by << 5, c0 = bx << 5;
  int tid = threadIdx.x;
#pragma unroll
  for (int i = 0; i < 4; i++) {
    int id = i * 256 + tid; int lr = id >> 5, lc = id & 31;
    t[lr][lc] = in[(size_t)(r0 + lr) * C + (c0 + lc)];
  }
  __syncthreads();
#pragma unroll
  for (int i = 0; i < 4; i++) {
    int id = i * 256 + tid; int lr = id >> 5, lc = id & 31;
    out[(size_t)(c0 + lr) * R + (r0 + lc)] = f2bf(t[lc][lr]);
  }
}

// ---------------- bf16 GEMM: C[M,N] = A[M,K] * Bt[N,K]^T ----------------
// BM=BN=256, BK=64, 512 thr = 8 waves (2M x 4N), per-wave 128x64 (acc[8][4]).
// LDS 128 KiB = 2 dbuf x (A 256x64 + B 256x64).
// ONE barrier per K-tile: issue all 24 ds_reads in pinned groups + 8 staging
// loads for tile t+1 (other buffer), then MFMA quadrants Q00,Q01,Q11,Q10 --
// compiler inserts exact counted lgkmcnt waits (12/8/0 staircase), so the
// tail ds_reads and the staging drain under the MFMA window. __syncthreads at
// tile end drains vmcnt+lgkm and provides the only sync point.
template <int OUT_BF16>
__global__ __launch_bounds__(512, 2) void gemm_bt(const u16* __restrict__ A,
                                                  const u16* __restrict__ Bt,
                                                  void* __restrict__ Cv,
                                                  int M, int N, int K) {
  __shared__ __align__(16) u16 lds2[2][32768];   // per dbuf: A[0..16383], B[16384..32767]
  int nbx = N >> 8;
  int nwg = gridDim.x;
  int bid = blockIdx.x;
  int cpx = nwg >> 3;                       // grids are multiples of 8
  int swz = (bid & 7) * cpx + (bid >> 3);
  int bx = swz % nbx, by = swz / nbx;
  int tid = threadIdx.x, lane = tid & 63, wv = tid >> 6;
  int wr = wv >> 2, wc = wv & 3;            // wave grid 2 (M) x 4 (N)
  int lr = lane & 15, g = lane >> 4;
  int rx = lr & 7;
  int rsub = lane >> 3;                     // staging: row within 8-row unit
  int clog = (lane & 7) ^ rsub;             // staging: logical (global) chunk

  const u16* Ap = A + (size_t)(by * 256) * K;
  const u16* Bp = Bt + (size_t)(bx * 256) * K;

  f32x4 acc[8][4];
#pragma unroll
  for (int m = 0; m < 8; m++)
#pragma unroll
    for (int n = 0; n < 4; n++) acc[m][n] = (f32x4){0.f, 0.f, 0.f, 0.f};

  short8 a0[4][2], a1[4][2], b0[2][2], b1[2][2];

#define ISSUE_A(HALF, L, T) do {                                                \
    int ru_ = (HALF) * 128 + (L) * 64 + wv * 8;                                 \
    const u16* g_ = Ap + (size_t)(ru_ + rsub) * K + (T) * 64 + clog * 8;        \
    __builtin_amdgcn_global_load_lds(                                           \
        (const __attribute__((address_space(1))) uint32_t*)g_,                  \
        (__attribute__((address_space(3))) uint32_t*)&lds2[(T) & 1][ru_ * 64],  \
        16, 0, 0);                                                              \
  } while (0)

#define ISSUE_B(HALF, L, T) do {                                                \
    int ru_ = (HALF) * 128 + (L) * 64 + wv * 8;                                 \
    const u16* g_ = Bp + (size_t)(ru_ + rsub) * K + (T) * 64 + clog * 8;        \
    __builtin_amdgcn_global_load_lds(                                           \
        (const __attribute__((address_space(1))) uint32_t*)g_,                  \
        (__attribute__((address_space(3)))                                      \
             uint32_t*)&lds2[(T) & 1][16384 + ru_ * 64],                        \
        16, 0, 0);                                                              \
  } while (0)

#define LDA(DST, MH, T) do {                                                    \
    _Pragma("unroll")                                                           \
    for (int m2 = 0; m2 < 4; m2++) {                                            \
      int row_ = wr * 128 + ((MH) * 4 + m2) * 16 + lr;                          \
      const u16* bp_ = &lds2[(T) & 1][row_ * 64];                               \
      _Pragma("unroll")                                                         \
      for (int s = 0; s < 2; s++)                                               \
        DST[m2][s] = *(const short8*)(bp_ + (((s * 4 + g) ^ rx) << 3));         \
    }                                                                           \
  } while (0)

#define LDB(DST, NHh, T) do {                                                   \
    _Pragma("unroll")                                                           \
    for (int n2 = 0; n2 < 2; n2++) {                                            \
      int row_ = wc * 64 + ((NHh) * 2 + n2) * 16 + lr;                          \
      const u16* bp_ = &lds2[(T) & 1][16384 + row_ * 64];                       \
      _Pragma("unroll")                                                         \
      for (int s = 0; s < 2; s++)                                               \
        DST[n2][s] = *(const short8*)(bp_ + (((s * 4 + g) ^ rx) << 3));         \
    }                                                                           \
  } while (0)

#define MFMA_Q(MH, NHh, AA, BB) do {                                            \
    _Pragma("unroll")                                                           \
    for (int s = 0; s < 2; s++)                                                 \
      _Pragma("unroll")                                                         \
      for (int m2 = 0; m2 < 4; m2++)                                            \
        _Pragma("unroll")                                                       \
        for (int n2 = 0; n2 < 2; n2++)                                          \
          acc[(MH) * 4 + m2][(NHh) * 2 + n2] =                                  \
              __builtin_amdgcn_mfma_f32_16x16x32_bf16(                          \
                  AA[m2][s], BB[n2][s], acc[(MH) * 4 + m2][(NHh) * 2 + n2],     \
                  0, 0, 0);                                                     \
  } while (0)

  int NT = K >> 6;
  // prologue: stage tile 0 into buf0, drain
  ISSUE_A(0, 0, 0); ISSUE_A(0, 1, 0); ISSUE_A(1, 0, 0); ISSUE_A(1, 1, 0);
  ISSUE_B(0, 0, 0); ISSUE_B(0, 1, 0); ISSUE_B(1, 0, 0); ISSUE_B(1, 1, 0);
  __syncthreads();

  for (int t = 0; t < NT; t++) {
    // group 1: frags for Q00
    LDA(a0, 0, t);
    LDB(b0, 0, t);
    __builtin_amdgcn_sched_barrier(0);
    // stage A of tile t+1 (other buffer; prior readers retired at last barrier)
    if (t + 1 < NT) {
      ISSUE_A(0, 0, t + 1); ISSUE_A(0, 1, t + 1);
      ISSUE_A(1, 0, t + 1); ISSUE_A(1, 1, t + 1);
    }
    __builtin_amdgcn_sched_barrier(0);
    // group 2: remaining frags
    LDB(b1, 1, t);
    LDA(a1, 1, t);
    __builtin_amdgcn_sched_barrier(0);
    // stage B of tile t+1
    if (t + 1 < NT) {
      ISSUE_B(0, 0, t + 1); ISSUE_B(0, 1, t + 1);
      ISSUE_B(1, 0, t + 1); ISSUE_B(1, 1, t + 1);
    }
    __builtin_amdgcn_sched_barrier(0);
    // MFMA staircase: compiler-counted lgkm waits (12 / 8 / 0)
    __builtin_amdgcn_s_setprio(1);
    MFMA_Q(0, 0, a0, b0);
    __builtin_amdgcn_sched_barrier(0);
    MFMA_Q(0, 1, a0, b1);
    __builtin_amdgcn_sched_barrier(0);
    MFMA_Q(1, 1, a1, b1);
    __builtin_amdgcn_sched_barrier(0);
    MFMA_Q(1, 0, a1, b0);
    __builtin_amdgcn_s_setprio(0);
    __syncthreads();   // drains own vmcnt (stages) + lgkm; one barrier per tile
  }

#undef ISSUE_A
#undef ISSUE_B
#undef LDA
#undef LDB
#undef MFMA_Q

  int rb = by * 256 + wr * 128, cb = bx * 256 + wc * 64;
#pragma unroll
  for (int m = 0; m < 8; m++)
#pragma unroll
    for (int n = 0; n < 4; n++)
#pragma unroll
      for (int r = 0; r < 4; r++) {
        int rg = rb + m * 16 + g * 4 + r;
        int cg = cb + n * 16 + lr;
        float v = acc[m][n][r];
        if (OUT_BF16)
          ((u16*)Cv)[(size_t)rg * N + cg] = f2bf(v);
        else
          ((float*)Cv)[(size_t)rg * N + cg] = v;
      }
}

// ---------------- chunk means of K and V (coalesced) ----------------
// block per (b, chunk): 256 blocks x 256 threads; thread owns 4 consecutive
// columns of the K segment (cols 1024..2047) and V segment (2048..3071).
__global__ __launch_bounds__(256) void chunk_sums(const u16* __restrict__ qkv,
                                                  float* __restrict__ ck,
                                                  float* __restrict__ cv) {
  int b = blockIdx.x >> 6, c = blockIdx.x & 63;
  int col = threadIdx.x * 4;
  const u16* base = qkv + (size_t)(b * SEQ + c * 64) * QKVC + 1024 + col;
  float sk0 = 0.f, sk1 = 0.f, sk2 = 0.f, sk3 = 0.f;
  float sv0 = 0.f, sv1 = 0.f, sv2 = 0.f, sv3 = 0.f;
#pragma unroll 8
  for (int r = 0; r < 64; r++) {
    ushort4 kk = *(const ushort4*)(base + (size_t)r * QKVC);
    ushort4 vv = *(const ushort4*)(base + (size_t)r * QKVC + 1024);
    sk0 += bf2f(kk.x); sk1 += bf2f(kk.y); sk2 += bf2f(kk.z); sk3 += bf2f(kk.w);
    sv0 += bf2f(vv.x); sv1 += bf2f(vv.y); sv2 += bf2f(vv.z); sv3 += bf2f(vv.w);
  }
  int h = col >> 6, d = col & 63;
  size_t o = (((size_t)(b * 16 + h)) * 64 + c) * 64 + d;
  ck[o]     = sk0 * 0.015625f; ck[o + 1] = sk1 * 0.015625f;
  ck[o + 2] = sk2 * 0.015625f; ck[o + 3] = sk3 * 0.015625f;
  cv[o]     = sv0 * 0.015625f; cv[o + 1] = sv1 * 0.015625f;
  cv[o + 2] = sv2 * 0.015625f; cv[o + 3] = sv3 * 0.015625f;
}

// ---------------- exclusive cumsum over chunks ----------------
__global__ void cumsum_excl(const float* __restrict__ ck, const float* __restrict__ cv,
                            float* __restrict__ cuk, float* __restrict__ cuv) {
  int bh = blockIdx.x;
  int d = threadIdx.x;
  float ak = 0.f, av = 0.f;
  for (int c = 0; c < 64; c++) {
    size_t i = ((size_t)bh * 64 + c) * 64 + d;
    cuk[i] = ak; cuv[i] = av;
    ak += ck[i]; av += cv[i];
  }
}

// ---------------- per-chunk attention + cross term ----------------
__global__ __launch_bounds__(256) void attn_kernel(const u16* __restrict__ qkv,
                                                   const float* __restrict__ cuk,
                                                   const float* __restrict__ cuv,
                                                   u16* __restrict__ out) {
  int blk = blockIdx.x;
  int c = blk & 63, h = (blk >> 6) & 15, b = blk >> 10;
  int row0 = b * SEQ + c * 64;
  __shared__ u16 q_s[64][80];
  __shared__ u16 k_s[64][80];
  __shared__ u16 vt_s[64][80];   // V transposed: vt_s[d][krow]
  __shared__ u16 p_s[64][80];
  __shared__ u16 ck_s[64];
  __shared__ float cv_s[64];
  int tid = threadIdx.x;
  {
    int r = tid >> 2, qt = tid & 3;
    const u16* rp = qkv + (size_t)(row0 + r) * QKVC + h * 64 + qt * 16;
    uint4 q0 = *(const uint4*)rp;          uint4 q1 = *(const uint4*)(rp + 8);
    uint4 k0 = *(const uint4*)(rp + 1024); uint4 k1 = *(const uint4*)(rp + 1032);
    uint4 v0 = *(const uint4*)(rp + 2048); uint4 v1 = *(const uint4*)(rp + 2056);
    *(uint4*)&q_s[r][qt * 16] = q0;     *(uint4*)&q_s[r][qt * 16 + 8] = q1;
    *(uint4*)&k_s[r][qt * 16] = k0;     *(uint4*)&k_s[r][qt * 16 + 8] = k1;
    const u16* vv0 = (const u16*)&v0;   const u16* vv1 = (const u16*)&v1;
#pragma unroll
    for (int j = 0; j < 8; j++) vt_s[qt * 16 + j][r] = vv0[j];
#pragma unroll
    for (int j = 0; j < 8; j++) vt_s[qt * 16 + 8 + j][r] = vv1[j];
    if (tid < 64) {
      ck_s[tid] = f2bf(cuk[(size_t)blk * 64 + tid]);
      cv_s[tid] = cuv[(size_t)blk * 64 + tid];
    }
  }
  __syncthreads();

  int lane = tid & 63, w = tid >> 6;
  int lr = lane & 15, g = lane >> 4;
  f32x4 accS[4];
#pragma unroll
  for (int n = 0; n < 4; n++) accS[n] = (f32x4){0.f, 0.f, 0.f, 0.f};
  f32x4 accC = (f32x4){0.f, 0.f, 0.f, 0.f};
  short8 zf = (short8){0, 0, 0, 0, 0, 0, 0, 0};
#pragma unroll
  for (int kt = 0; kt < 2; kt++) {
    int lk = kt * 32 + g * 8;
    short8 af = *(const short8*)&q_s[w * 16 + lr][lk];
    short8 cf = (lr == 0) ? *(const short8*)&ck_s[lk] : zf;
    accC = __builtin_amdgcn_mfma_f32_16x16x32_bf16(af, cf, accC, 0, 0, 0);
#pragma unroll
    for (int n = 0; n < 4; n++) {
      short8 bf = *(const short8*)&k_s[n * 16 + lr][lk];
      accS[n] = __builtin_amdgcn_mfma_f32_16x16x32_bf16(af, bf, accS[n], 0, 0, 0);
    }
  }
  float crossv[4];
#pragma unroll
  for (int r4 = 0; r4 < 4; r4++) {
    int row = w * 16 + g * 4 + r4;
    float x[4];
    float mx = -3.4e38f;
#pragma unroll
    for (int n = 0; n < 4; n++) {
      int col = n * 16 + lr;
      x[n] = ((col & 63) > (row & 63)) ? -65000.0f : accS[n][r4] * SCALE;
      mx = fmaxf(mx, x[n]);
    }
    mx = fmaxf(mx, __shfl_xor(mx, 1));
    mx = fmaxf(mx, __shfl_xor(mx, 2));
    mx = fmaxf(mx, __shfl_xor(mx, 4));
    mx = fmaxf(mx, __shfl_xor(mx, 8));
    float p[4], sum = 0.f;
#pragma unroll
    for (int n = 0; n < 4; n++) { p[n] = __expf(x[n] - mx); sum += p[n]; }
    sum += __shfl_xor(sum, 1);
    sum += __shfl_xor(sum, 2);
    sum += __shfl_xor(sum, 4);
    sum += __shfl_xor(sum, 8);
    float inv = 1.0f / sum;
#pragma unroll
    for (int n = 0; n < 4; n++) p_s[row][n * 16 + lr] = f2bf(p[n] * inv);
    float sg = 1.0f / (1.0f + __expf(-accC[r4] * SCALE));
    crossv[r4] = __shfl(sg, (lane & 48));
  }
  __syncthreads();
  f32x4 accO[4];
#pragma unroll
  for (int n = 0; n < 4; n++) accO[n] = (f32x4){0.f, 0.f, 0.f, 0.f};
#pragma unroll
  for (int kt = 0; kt < 2; kt++) {
    int lk = kt * 32 + g * 8;
    short8 pf = *(const short8*)&p_s[w * 16 + lr][lk];
#pragma unroll
    for (int n = 0; n < 4; n++) {
      short8 vf = *(const short8*)&vt_s[n * 16 + lr][lk];
      accO[n] = __builtin_amdgcn_mfma_f32_16x16x32_bf16(pf, vf, accO[n], 0, 0, 0);
    }
  }
#pragma unroll
  for (int n = 0; n < 4; n++)
#pragma unroll
    for (int r4 = 0; r4 < 4; r4++) {
      int row = w * 16 + g * 4 + r4;
      int col = n * 16 + lr;
      float v = accO[n][r4] + crossv[r4] * cv_s[col] * 0.5f;
      out[(size_t)(row0 + row) * DIMC + h * 64 + col] = f2bf(v);
    }
}

extern "C" void kernel_launch(void* const* d_in, const int* in_sizes, int n_in,
                              void* d_out, int out_size, void* d_ws, size_t ws_size,
                              hipStream_t stream) {
  const float* x = (const float*)d_in[0];
  const float* Wqkv = (const float*)d_in[1];
  const float* Wout = (const float*)d_in[2];
  char* ws = (char*)d_ws;
  size_t off = 0;
  auto alloc = [&](size_t b) {
    void* p = ws + off;
    off += (b + 255) & ~(size_t)255;
    return p;
  };
  u16* xb = (u16*)alloc((size_t)NROWS * DIMC * 2);        // 32MB, reused as attnb
  u16* wqt = (u16*)alloc((size_t)QKVC * DIMC * 2);        // 6MB
  u16* wot = (u16*)alloc((size_t)DIMC * DIMC * 2);        // 2MB
  u16* qkvb = (u16*)alloc((size_t)NROWS * QKVC * 2);      // 96MB
  float* chk = (float*)alloc((size_t)4096 * 64 * 4);
  float* chv = (float*)alloc((size_t)4096 * 64 * 4);
  float* cuk = (float*)alloc((size_t)4096 * 64 * 4);
  float* cuv = (float*)alloc((size_t)4096 * 64 * 4);
  u16* attnb = xb;

  cvt_kernel<<<16384, 256, 0, stream>>>(x, xb, NROWS * DIMC / 4);
  transpose_cvt<<<3072, 256, 0, stream>>>(Wqkv, wqt, DIMC, QKVC);
  transpose_cvt<<<1024, 256, 0, stream>>>(Wout, wot, DIMC, DIMC);
  gemm_bt<1><<<768, 512, 0, stream>>>(xb, wqt, qkvb, NROWS, QKVC, DIMC);
  chunk_sums<<<256, 256, 0, stream>>>(qkvb, chk, chv);
  cumsum_excl<<<64, 64, 0, stream>>>(chk, chv, cuk, cuv);
  attn_kernel<<<4096, 256, 0, stream>>>(qkvb, cuk, cuv, attnb);
  gemm_bt<0><<<256, 512, 0, stream>>>(attnb, wot, d_out, NROWS, DIMC, DIMC);
}

// Round 6
// 203.525 us; speedup vs baseline: 1.2625x; 1.0522x over previous
//
#include <hip/hip_runtime.h>
#include <stdint.h>

typedef __attribute__((ext_vector_type(4))) float f32x4;
typedef __attribute__((ext_vector_type(8))) short short8;
typedef unsigned short u16;

#define NH 16
#define HD 64
#define SEQ 4096
#define BATCH 4
#define NROWS (BATCH * SEQ)      // 16384
#define DIMC 1024
#define QKVC 3072
#define SCALE 0.125f

__device__ __forceinline__ u16 f2bf(float f) {
  union { float f; uint32_t u; } v; v.f = f;
  uint32_t u = v.u;
  uint32_t r = (u + 0x7fffu + ((u >> 16) & 1u)) >> 16;
  return (u16)r;
}
__device__ __forceinline__ float bf2f(u16 h) {
  union { uint32_t u; float f; } v; v.u = ((uint32_t)h) << 16;
  return v.f;
}

// ---------------- fp32 -> bf16 elementwise convert (vectorized) ----------------
__global__ __launch_bounds__(256) void cvt_kernel(const float* __restrict__ in,
                                                  u16* __restrict__ out, int n4) {
  int i = blockIdx.x * 256 + threadIdx.x;
  if (i >= n4) return;
  float4 v = ((const float4*)in)[i];
  ushort4 o;
  o.x = f2bf(v.x); o.y = f2bf(v.y); o.z = f2bf(v.z); o.w = f2bf(v.w);
  ((ushort4*)out)[i] = o;
}

// ---------------- fp32 [R][C] -> bf16 [C][R] transpose ----------------
__global__ __launch_bounds__(256) void transpose_cvt(const float* __restrict__ in,
                                                     u16* __restrict__ out, int R, int C) {
  __shared__ float t[32][33];
  int nbx = C >> 5;
  int bx = blockIdx.x % nbx, by = blockIdx.x / nbx;
  int r0 = by << 5, c0 = bx << 5;
  int tid = threadIdx.x;
#pragma unroll
  for (int i = 0; i < 4; i++) {
    int id = i * 256 + tid; int lr = id >> 5, lc = id & 31;
    t[lr][lc] = in[(size_t)(r0 + lr) * C + (c0 + lc)];
  }
  __syncthreads();
#pragma unroll
  for (int i = 0; i < 4; i++) {
    int id = i * 256 + tid; int lr = id >> 5, lc = id & 31;
    out[(size_t)(c0 + lr) * R + (r0 + lc)] = f2bf(t[lc][lr]);
  }
}

// ---------------- bf16 GEMM: C[M,N] = A[M,K] * Bt[N,K]^T ----------------
// BM=BN=256, BK=64, 512 thr = 8 waves (2M x 4N), per-wave 128x64 (acc[8][4]).
// LDS 128 KiB = 2 dbuf x (A 256x64 + B 256x64).
// Cross-phase pipelined: each MFMA quadrant consumes frags read >=1 phase
// earlier (quadrant order Q00,Q01,Q10,Q11 so preload targets are dead regs).
//   P1: rd b1    | stage A(t+1) | Q00(a0,b0)  | barrier
//   P2: rd a1    | stage B(t+1) | Q01(a0,b1)  | barrier      (a0 dies)
//   P3:            Q10(a1,b0); vmcnt(0); barrier             (b0 dies)
//   P4: rd a0',b0' (from buf^1) | Q11(a1,b1)  | barrier
// DO_SUMS: fused per-chunk column means of K/V from fp32 acc (chunk_sums
// kernel eliminated). Each chunk element is owned by exactly one wave.
template <int OUT_BF16, int DO_SUMS>
__global__ __launch_bounds__(512, 2) void gemm_bt(const u16* __restrict__ A,
                                                  const u16* __restrict__ Bt,
                                                  void* __restrict__ Cv,
                                                  float* __restrict__ chk,
                                                  float* __restrict__ chv,
                                                  int M, int N, int K) {
  __shared__ __align__(16) u16 lds2[2][32768];   // per dbuf: A[0..16383], B[16384..32767]
  int nbx = N >> 8;
  int nwg = gridDim.x;
  int bid = blockIdx.x;
  int cpx = nwg >> 3;                       // grids are multiples of 8
  int swz = (bid & 7) * cpx + (bid >> 3);
  int bx = swz % nbx, by = swz / nbx;
  int tid = threadIdx.x, lane = tid & 63, wv = tid >> 6;
  int wr = wv >> 2, wc = wv & 3;            // wave grid 2 (M) x 4 (N)
  int lr = lane & 15, g = lane >> 4;
  int rx = lr & 7;
  int rsub = lane >> 3;                     // staging: row within 8-row unit
  int clog = (lane & 7) ^ rsub;             // staging: logical (global) chunk

  const u16* Ap = A + (size_t)(by * 256) * K;
  const u16* Bp = Bt + (size_t)(bx * 256) * K;

  f32x4 acc[8][4];
#pragma unroll
  for (int m = 0; m < 8; m++)
#pragma unroll
    for (int n = 0; n < 4; n++) acc[m][n] = (f32x4){0.f, 0.f, 0.f, 0.f};

  short8 a0[4][2], a1[4][2], b0[2][2], b1[2][2];

#define ISSUE_A(HALF, L, T) do {                                                \
    int ru_ = (HALF) * 128 + (L) * 64 + wv * 8;                                 \
    const u16* g_ = Ap + (size_t)(ru_ + rsub) * K + (T) * 64 + clog * 8;        \
    __builtin_amdgcn_global_load_lds(                                           \
        (const __attribute__((address_space(1))) uint32_t*)g_,                  \
        (__attribute__((address_space(3))) uint32_t*)&lds2[(T) & 1][ru_ * 64],  \
        16, 0, 0);                                                              \
  } while (0)

#define ISSUE_B(HALF, L, T) do {                                                \
    int ru_ = (HALF) * 128 + (L) * 64 + wv * 8;                                 \
    const u16* g_ = Bp + (size_t)(ru_ + rsub) * K + (T) * 64 + clog * 8;        \
    __builtin_amdgcn_global_load_lds(                                           \
        (const __attribute__((address_space(1))) uint32_t*)g_,                  \
        (__attribute__((address_space(3)))                                      \
             uint32_t*)&lds2[(T) & 1][16384 + ru_ * 64],                        \
        16, 0, 0);                                                              \
  } while (0)

#define LDA(DST, MH, T) do {                                                    \
    _Pragma("unroll")                                                           \
    for (int m2 = 0; m2 < 4; m2++) {                                            \
      int row_ = wr * 128 + ((MH) * 4 + m2) * 16 + lr;                          \
      const u16* bp_ = &lds2[(T) & 1][row_ * 64];                               \
      _Pragma("unroll")                                                         \
      for (int s = 0; s < 2; s++)                                               \
        DST[m2][s] = *(const short8*)(bp_ + (((s * 4 + g) ^ rx) << 3));         \
    }                                                                           \
  } while (0)

#define LDB(DST, NHh, T) do {                                                   \
    _Pragma("unroll")                                                           \
    for (int n2 = 0; n2 < 2; n2++) {                                            \
      int row_ = wc * 64 + ((NHh) * 2 + n2) * 16 + lr;                          \
      const u16* bp_ = &lds2[(T) & 1][16384 + row_ * 64];                       \
      _Pragma("unroll")                                                         \
      for (int s = 0; s < 2; s++)                                               \
        DST[n2][s] = *(const short8*)(bp_ + (((s * 4 + g) ^ rx) << 3));         \
    }                                                                           \
  } while (0)

#define MFMA_Q(MH, NHh, AA, BB) do {                                            \
    _Pragma("unroll")                                                           \
    for (int s = 0; s < 2; s++)                                                 \
      _Pragma("unroll")                                                         \
      for (int m2 = 0; m2 < 4; m2++)                                            \
        _Pragma("unroll")                                                       \
        for (int n2 = 0; n2 < 2; n2++)                                          \
          acc[(MH) * 4 + m2][(NHh) * 2 + n2] =                                  \
              __builtin_amdgcn_mfma_f32_16x16x32_bf16(                          \
                  AA[m2][s], BB[n2][s], acc[(MH) * 4 + m2][(NHh) * 2 + n2],     \
                  0, 0, 0);                                                     \
  } while (0)

  int NT = K >> 6;
  // prologue: stage tile 0, drain, preload a0/b0 of tile 0
  ISSUE_A(0, 0, 0); ISSUE_A(0, 1, 0); ISSUE_A(1, 0, 0); ISSUE_A(1, 1, 0);
  ISSUE_B(0, 0, 0); ISSUE_B(0, 1, 0); ISSUE_B(1, 0, 0); ISSUE_B(1, 1, 0);
  asm volatile("s_waitcnt vmcnt(0)" ::: "memory");
  __builtin_amdgcn_s_barrier();
  LDA(a0, 0, 0);
  LDB(b0, 0, 0);
  __builtin_amdgcn_sched_barrier(0);

  for (int t = 0; t < NT; t++) {
    // ---- P1: rd b1 | stage A(t+1) | Q00(a0,b0)
    LDB(b1, 1, t);
    if (t + 1 < NT) {
      ISSUE_A(0, 0, t + 1); ISSUE_A(0, 1, t + 1);
      ISSUE_A(1, 0, t + 1); ISSUE_A(1, 1, t + 1);
    }
    __builtin_amdgcn_sched_barrier(0);
    __builtin_amdgcn_s_setprio(1);
    MFMA_Q(0, 0, a0, b0);
    __builtin_amdgcn_s_setprio(0);
    __builtin_amdgcn_sched_barrier(0);
    __builtin_amdgcn_s_barrier();
    // ---- P2: rd a1 | stage B(t+1) | Q01(a0,b1)   [a0 dead after]
    LDA(a1, 1, t);
    if (t + 1 < NT) {
      ISSUE_B(0, 0, t + 1); ISSUE_B(0, 1, t + 1);
      ISSUE_B(1, 0, t + 1); ISSUE_B(1, 1, t + 1);
    }
    __builtin_amdgcn_sched_barrier(0);
    __builtin_amdgcn_s_setprio(1);
    MFMA_Q(0, 1, a0, b1);
    __builtin_amdgcn_s_setprio(0);
    __builtin_amdgcn_sched_barrier(0);
    __builtin_amdgcn_s_barrier();
    // ---- P3: Q10(a1,b0); vmcnt retires tile t+1 stages   [b0 dead after]
    __builtin_amdgcn_s_setprio(1);
    MFMA_Q(1, 0, a1, b0);
    __builtin_amdgcn_s_setprio(0);
    __builtin_amdgcn_sched_barrier(0);
    asm volatile("s_waitcnt vmcnt(0)" ::: "memory");
    __builtin_amdgcn_s_barrier();
    // ---- P4: preload a0',b0' from buf^1 | Q11(a1,b1)
    if (t + 1 < NT) {
      LDA(a0, 0, t + 1);
      LDB(b0, 0, t + 1);
    }
    __builtin_amdgcn_sched_barrier(0);
    __builtin_amdgcn_s_setprio(1);
    MFMA_Q(1, 1, a1, b1);
    __builtin_amdgcn_s_setprio(0);
    __builtin_amdgcn_sched_barrier(0);
    __builtin_amdgcn_s_barrier();
  }

#undef ISSUE_A
#undef ISSUE_B
#undef LDA
#undef LDB
#undef MFMA_Q

  int rb = by * 256 + wr * 128, cb = bx * 256 + wc * 64;

  if (DO_SUMS && cb >= 1024) {
    // fused chunk means: wave owns chunks (wr*2+mh); sum fp32 acc over rows.
#pragma unroll
    for (int mh = 0; mh < 2; mh++)
#pragma unroll
      for (int n = 0; n < 4; n++) {
        float sum = 0.f;
#pragma unroll
        for (int m = mh * 4; m < mh * 4 + 4; m++)
#pragma unroll
          for (int r = 0; r < 4; r++) sum += acc[m][n][r];
        sum += __shfl_xor(sum, 16);
        sum += __shfl_xor(sum, 32);
        if (g == 0) {
          int grb = rb + mh * 64;
          int b = grb >> 12, c = (grb >> 6) & 63;
          int cg = cb + n * 16 + lr;
          int col = cg & 1023;
          int h = col >> 6, d = col & 63;
          float* dst = (cg < 2048) ? chk : chv;
          dst[(((size_t)(b * 16 + h)) * 64 + c) * 64 + d] = sum * 0.015625f;
        }
      }
  }

#pragma unroll
  for (int m = 0; m < 8; m++)
#pragma unroll
    for (int n = 0; n < 4; n++)
#pragma unroll
      for (int r = 0; r < 4; r++) {
        int rg = rb + m * 16 + g * 4 + r;
        int cg = cb + n * 16 + lr;
        float v = acc[m][n][r];
        if (OUT_BF16)
          ((u16*)Cv)[(size_t)rg * N + cg] = f2bf(v);
        else
          ((float*)Cv)[(size_t)rg * N + cg] = v;
      }
}

// ---------------- exclusive cumsum over chunks ----------------
__global__ void cumsum_excl(const float* __restrict__ ck, const float* __restrict__ cv,
                            float* __restrict__ cuk, float* __restrict__ cuv) {
  int bh = blockIdx.x;
  int d = threadIdx.x;
  float ak = 0.f, av = 0.f;
  for (int c = 0; c < 64; c++) {
    size_t i = ((size_t)bh * 64 + c) * 64 + d;
    cuk[i] = ak; cuv[i] = av;
    ak += ck[i]; av += cv[i];
  }
}

// ---------------- per-chunk attention + cross term ----------------
__global__ __launch_bounds__(256) void attn_kernel(const u16* __restrict__ qkv,
                                                   const float* __restrict__ cuk,
                                                   const float* __restrict__ cuv,
                                                   u16* __restrict__ out) {
  int blk = blockIdx.x;
  int c = blk & 63, h = (blk >> 6) & 15, b = blk >> 10;
  int row0 = b * SEQ + c * 64;
  __shared__ u16 q_s[64][80];
  __shared__ u16 k_s[64][80];
  __shared__ u16 vt_s[64][80];   // V transposed: vt_s[d][krow]
  __shared__ u16 p_s[64][80];
  __shared__ u16 ck_s[64];
  __shared__ float cv_s[64];
  int tid = threadIdx.x;
  {
    int r = tid >> 2, qt = tid & 3;
    const u16* rp = qkv + (size_t)(row0 + r) * QKVC + h * 64 + qt * 16;
    uint4 q0 = *(const uint4*)rp;          uint4 q1 = *(const uint4*)(rp + 8);
    uint4 k0 = *(const uint4*)(rp + 1024); uint4 k1 = *(const uint4*)(rp + 1032);
    uint4 v0 = *(const uint4*)(rp + 2048); uint4 v1 = *(const uint4*)(rp + 2056);
    *(uint4*)&q_s[r][qt * 16] = q0;     *(uint4*)&q_s[r][qt * 16 + 8] = q1;
    *(uint4*)&k_s[r][qt * 16] = k0;     *(uint4*)&k_s[r][qt * 16 + 8] = k1;
    const u16* vv0 = (const u16*)&v0;   const u16* vv1 = (const u16*)&v1;
#pragma unroll
    for (int j = 0; j < 8; j++) vt_s[qt * 16 + j][r] = vv0[j];
#pragma unroll
    for (int j = 0; j < 8; j++) vt_s[qt * 16 + 8 + j][r] = vv1[j];
    if (tid < 64) {
      ck_s[tid] = f2bf(cuk[(size_t)blk * 64 + tid]);
      cv_s[tid] = cuv[(size_t)blk * 64 + tid];
    }
  }
  __syncthreads();

  int lane = tid & 63, w = tid >> 6;
  int lr = lane & 15, g = lane >> 4;
  f32x4 accS[4];
#pragma unroll
  for (int n = 0; n < 4; n++) accS[n] = (f32x4){0.f, 0.f, 0.f, 0.f};
  f32x4 accC = (f32x4){0.f, 0.f, 0.f, 0.f};
  short8 zf = (short8){0, 0, 0, 0, 0, 0, 0, 0};
#pragma unroll
  for (int kt = 0; kt < 2; kt++) {
    int lk = kt * 32 + g * 8;
    short8 af = *(const short8*)&q_s[w * 16 + lr][lk];
    short8 cf = (lr == 0) ? *(const short8*)&ck_s[lk] : zf;
    accC = __builtin_amdgcn_mfma_f32_16x16x32_bf16(af, cf, accC, 0, 0, 0);
#pragma unroll
    for (int n = 0; n < 4; n++) {
      short8 bf = *(const short8*)&k_s[n * 16 + lr][lk];
      accS[n] = __builtin_amdgcn_mfma_f32_16x16x32_bf16(af, bf, accS[n], 0, 0, 0);
    }
  }
  float crossv[4];
#pragma unroll
  for (int r4 = 0; r4 < 4; r4++) {
    int row = w * 16 + g * 4 + r4;
    float x[4];
    float mx = -3.4e38f;
#pragma unroll
    for (int n = 0; n < 4; n++) {
      int col = n * 16 + lr;
      x[n] = ((col & 63) > (row & 63)) ? -65000.0f : accS[n][r4] * SCALE;
      mx = fmaxf(mx, x[n]);
    }
    mx = fmaxf(mx, __shfl_xor(mx, 1));
    mx = fmaxf(mx, __shfl_xor(mx, 2));
    mx = fmaxf(mx, __shfl_xor(mx, 4));
    mx = fmaxf(mx, __shfl_xor(mx, 8));
    float p[4], sum = 0.f;
#pragma unroll
    for (int n = 0; n < 4; n++) { p[n] = __expf(x[n] - mx); sum += p[n]; }
    sum += __shfl_xor(sum, 1);
    sum += __shfl_xor(sum, 2);
    sum += __shfl_xor(sum, 4);
    sum += __shfl_xor(sum, 8);
    float inv = 1.0f / sum;
#pragma unroll
    for (int n = 0; n < 4; n++) p_s[row][n * 16 + lr] = f2bf(p[n] * inv);
    float sg = 1.0f / (1.0f + __expf(-accC[r4] * SCALE));
    crossv[r4] = __shfl(sg, (lane & 48));
  }
  __syncthreads();
  f32x4 accO[4];
#pragma unroll
  for (int n = 0; n < 4; n++) accO[n] = (f32x4){0.f, 0.f, 0.f, 0.f};
#pragma unroll
  for (int kt = 0; kt < 2; kt++) {
    int lk = kt * 32 + g * 8;
    short8 pf = *(const short8*)&p_s[w * 16 + lr][lk];
#pragma unroll
    for (int n = 0; n < 4; n++) {
      short8 vf = *(const short8*)&vt_s[n * 16 + lr][lk];
      accO[n] = __builtin_amdgcn_mfma_f32_16x16x32_bf16(pf, vf, accO[n], 0, 0, 0);
    }
  }
#pragma unroll
  for (int n = 0; n < 4; n++)
#pragma unroll
    for (int r4 = 0; r4 < 4; r4++) {
      int row = w * 16 + g * 4 + r4;
      int col = n * 16 + lr;
      float v = accO[n][r4] + crossv[r4] * cv_s[col] * 0.5f;
      out[(size_t)(row0 + row) * DIMC + h * 64 + col] = f2bf(v);
    }
}

extern "C" void kernel_launch(void* const* d_in, const int* in_sizes, int n_in,
                              void* d_out, int out_size, void* d_ws, size_t ws_size,
                              hipStream_t stream) {
  const float* x = (const float*)d_in[0];
  const float* Wqkv = (const float*)d_in[1];
  const float* Wout = (const float*)d_in[2];
  char* ws = (char*)d_ws;
  size_t off = 0;
  auto alloc = [&](size_t b) {
    void* p = ws + off;
    off += (b + 255) & ~(size_t)255;
    return p;
  };
  u16* xb = (u16*)alloc((size_t)NROWS * DIMC * 2);        // 32MB, reused as attnb
  u16* wqt = (u16*)alloc((size_t)QKVC * DIMC * 2);        // 6MB
  u16* wot = (u16*)alloc((size_t)DIMC * DIMC * 2);        // 2MB
  u16* qkvb = (u16*)alloc((size_t)NROWS * QKVC * 2);      // 96MB
  float* chk = (float*)alloc((size_t)4096 * 64 * 4);
  float* chv = (float*)alloc((size_t)4096 * 64 * 4);
  float* cuk = (float*)alloc((size_t)4096 * 64 * 4);
  float* cuv = (float*)alloc((size_t)4096 * 64 * 4);
  u16* attnb = xb;

  cvt_kernel<<<16384, 256, 0, stream>>>(x, xb, NROWS * DIMC / 4);
  transpose_cvt<<<3072, 256, 0, stream>>>(Wqkv, wqt, DIMC, QKVC);
  transpose_cvt<<<1024, 256, 0, stream>>>(Wout, wot, DIMC, DIMC);
  gemm_bt<1, 1><<<768, 512, 0, stream>>>(xb, wqt, qkvb, chk, chv, NROWS, QKVC, DIMC);
  cumsum_excl<<<64, 64, 0, stream>>>(chk, chv, cuk, cuv);
  attn_kernel<<<4096, 256, 0, stream>>>(qkvb, cuk, cuv, attnb);
  gemm_bt<0, 0><<<256, 512, 0, stream>>>(attnb, wot, d_out, nullptr, nullptr,
                                         NROWS, DIMC, DIMC);
}